// Round 1
// baseline (398.304 us; speedup 1.0000x reference)
//
#include <hip/hip_runtime.h>
#include <math.h>

// dims
#define RN   16      // rims
#define CN   64      // channels
#define HDN  4       // heads
#define DN   16      // depth
#define KN   4       // top-k
#define HWN  4096    // 64*64 pixels per image
#define NPIX 32768   // B*H*W
#define OCN  1024    // R*HD*D
#define CHW  (CN*HWN)

// One block = 64 pixels (one tile). 256 threads.
// Phases: q/ip_null -> scores (4 waves x 4 rims) -> top4+binning -> binned
// val+merge (rim-uniform waves, LDS fp32 atomic accumulate) -> Wo projection.
__global__ __launch_bounds__(256) void rims_fused(
    const float* __restrict__ x,   const float* __restrict__ rims,
    const float* __restrict__ Wk,  const float* __restrict__ bk,
    const float* __restrict__ Wv,  const float* __restrict__ bv,
    const float* __restrict__ Wq,  const float* __restrict__ bq,
    const float* __restrict__ Wm,  const float* __restrict__ bm,
    const float* __restrict__ Wo,  const float* __restrict__ bo,
    float* __restrict__ out)
{
  __shared__ float q_s[OCN];         // 4 KB   relu(Wq rims + bq)
  __shared__ float ipn_s[64];        //        null-branch logits per (r,h)
  __shared__ float sc_s[16 * 65];    // 4.2 KB scores [r][pix], pad 65
  __shared__ float macc_s[64 * 65];  // 16.6KB merged-sum accum [pix][c], pad 65
  __shared__ int   bcnt[16];
  __shared__ int   bpos[16];
  __shared__ unsigned char brim[256];
  __shared__ unsigned char bpix[256];

  const int tid   = threadIdx.x;
  const int tile  = blockIdx.x;          // 0..511
  const int b     = tile >> 6;           // image index
  const int pbase = (tile & 63) * 64;    // pixel offset within image
  const float* xbase = x + (size_t)b * CHW + pbase;

  // ---- P0: q = relu(Wq . rims + bq), per-block recompute (65K MACs, tiny) ----
  for (int o = tid; o < OCN; o += 256) {
    const int r = o >> 6;
    const float* wq = Wq + o * CN;
    const float* rp = rims + r * CN;
    float a0 = bq[o], a1 = 0.f, a2 = 0.f, a3 = 0.f;
    #pragma unroll
    for (int c = 0; c < CN; c += 4) {
      a0 = fmaf(wq[c+0], rp[c+0], a0);
      a1 = fmaf(wq[c+1], rp[c+1], a1);
      a2 = fmaf(wq[c+2], rp[c+2], a2);
      a3 = fmaf(wq[c+3], rp[c+3], a3);
    }
    q_s[o] = fmaxf((a0 + a1) + (a2 + a3), 0.f);
  }
  __syncthreads();
  if (tid < 64) {   // ip_null[rh] = sum_d relu(bk) * q   (zero-input branch)
    float acc = 0.f;
    #pragma unroll
    for (int d = 0; d < DN; ++d)
      acc = fmaf(fmaxf(bk[tid * DN + d], 0.f), q_s[tid * DN + d], acc);
    ipn_s[tid] = acc;
  }
  __syncthreads();

  // ---- P1: scores. wave g handles rims 4g..4g+3 for all 64 pixels ----
  {
    const int pl = tid & 63;
    const int g  = tid >> 6;
    const float* xp = xbase + pl;
    float xv[CN];
    #pragma unroll
    for (int c = 0; c < CN; ++c) xv[c] = xp[c * HWN];   // coalesced, L1-hot

    #pragma unroll 1
    for (int rr = 0; rr < 4; ++rr) {
      const int r = g * 4 + rr;
      float score = 0.f;
      #pragma unroll 1
      for (int h = 0; h < HDN; ++h) {
        const int rh = r * HDN + h;
        float qrow[DN];
        #pragma unroll
        for (int d = 0; d < DN; ++d) qrow[d] = q_s[rh * DN + d];
        const float ipn = ipn_s[rh];
        float ip = 0.f;
        #pragma unroll 1
        for (int d = 0; d < DN; ++d) {
          const float qv = qrow[d];
          if (qv != 0.f) {      // uniform across wave: real skip (~50% of rows)
            const int o = rh * DN + d;
            const float* w = Wk + o * CN;   // uniform addr -> scalar loads
            float a0 = bk[o], a1 = 0.f, a2 = 0.f, a3 = 0.f;
            #pragma unroll
            for (int c = 0; c < CN; c += 4) {
              a0 = fmaf(w[c+0], xv[c+0], a0);
              a1 = fmaf(w[c+1], xv[c+1], a1);
              a2 = fmaf(w[c+2], xv[c+2], a2);
              a3 = fmaf(w[c+3], xv[c+3], a3);
            }
            ip = fmaf(fmaxf((a0 + a1) + (a2 + a3), 0.f), qv, ip);
          }
        }
        // softmax over {real, null} == sigmoid(ip - ipn)
        score += 1.f / (1.f + expf(ipn - ip));
      }
      sc_s[r * 65 + pl] = score;
    }
  }
  __syncthreads();

  // ---- P2: zero accum, top-4 selection, block-local rim binning ----
  for (int i = tid; i < 64 * 65; i += 256) macc_s[i] = 0.f;
  if (tid < 16) bcnt[tid] = 0;
  __syncthreads();

  int rs0 = 0, rs1 = 0, rs2 = 0, rs3 = 0;
  if (tid < 64) {
    float s[RN];
    #pragma unroll
    for (int r = 0; r < RN; ++r) s[r] = sc_s[r * 65 + tid];
    // strict > picks first (lowest-index) max: matches jax.lax.top_k tie order
    #pragma unroll
    for (int k = 0; k < KN; ++k) {
      float best = -3.4e38f; int bi = 0;
      #pragma unroll
      for (int r = 0; r < RN; ++r) { if (s[r] > best) { best = s[r]; bi = r; } }
      if (k == 0) rs0 = bi; else if (k == 1) rs1 = bi;
      else if (k == 2) rs2 = bi; else rs3 = bi;
      s[bi] = -3.4e38f;
    }
    atomicAdd(&bcnt[rs0], 1); atomicAdd(&bcnt[rs1], 1);
    atomicAdd(&bcnt[rs2], 1); atomicAdd(&bcnt[rs3], 1);
  }
  __syncthreads();
  if (tid == 0) {
    int run = 0;
    #pragma unroll
    for (int r = 0; r < RN; ++r) { bpos[r] = run; run += bcnt[r]; }
  }
  __syncthreads();
  if (tid < 64) {
    int p0 = atomicAdd(&bpos[rs0], 1); brim[p0] = (unsigned char)rs0; bpix[p0] = (unsigned char)tid;
    int p1 = atomicAdd(&bpos[rs1], 1); brim[p1] = (unsigned char)rs1; bpix[p1] = (unsigned char)tid;
    int p2 = atomicAdd(&bpos[rs2], 1); brim[p2] = (unsigned char)rs2; bpix[p2] = (unsigned char)tid;
    int p3 = atomicAdd(&bpos[rs3], 1); brim[p3] = (unsigned char)rs3; bpix[p3] = (unsigned char)tid;
  }
  __syncthreads();

  // ---- P3: one binned (pixel, rim) entry per thread. Waves are mostly
  // rim-uniform (sorted by rim) -> weight gathers hit 1-3 cache lines. ----
  {
    const int rim = (int)brim[tid];
    const int pp  = (int)bpix[tid];
    const float* xp = xbase + pp;          // pixels within tile: <=4 lines/load
    float xv[CN];
    #pragma unroll
    for (int c = 0; c < CN; ++c) xv[c] = xp[c * HWN];

    float macc[CN];
    const float* bmp = bm + rim * CN;
    #pragma unroll
    for (int c = 0; c < CN; ++c) macc[c] = bmp[c];

    const float* wvb = Wv + (size_t)(rim * 64) * CN;
    const float* bvp = bv + rim * 64;
    const float* wmb = Wm + (size_t)(rim * CN) * 64;

    #pragma unroll 1
    for (int d0 = 0; d0 < 64; d0 += 8) {   // 8 val channels per pass
      float vald[8];
      #pragma unroll
      for (int k8 = 0; k8 < 8; ++k8) {
        const int d = d0 + k8;
        const float* w = wvb + d * CN;
        float a0 = bvp[d], a1 = 0.f, a2 = 0.f, a3 = 0.f;
        #pragma unroll
        for (int c = 0; c < CN; c += 4) {
          a0 = fmaf(w[c+0], xv[c+0], a0);
          a1 = fmaf(w[c+1], xv[c+1], a1);
          a2 = fmaf(w[c+2], xv[c+2], a2);
          a3 = fmaf(w[c+3], xv[c+3], a3);
        }
        vald[k8] = fmaxf((a0 + a1) + (a2 + a3), 0.f);
      }
      #pragma unroll
      for (int c = 0; c < CN; ++c) {
        const float* wm = wmb + c * 64 + d0;   // row-contiguous Wm
        float m = macc[c];
        #pragma unroll
        for (int k8 = 0; k8 < 8; ++k8) m = fmaf(wm[k8], vald[k8], m);
        macc[c] = m;
      }
    }
    #pragma unroll
    for (int c = 0; c < CN; ++c)
      atomicAdd(&macc_s[pp * 65 + c], macc[c]);   // ds_add_f32, padded banks
  }
  __syncthreads();

  // ---- P4: u = relu(mean), out = relu(Wo u + bo). lane=pixel, wave=ch/16 ----
  {
    const int j  = tid >> 6;
    const int pl = tid & 63;
    float u[CN];
    #pragma unroll
    for (int c = 0; c < CN; ++c)
      u[c] = fmaxf(macc_s[pl * 65 + c] * 0.25f, 0.f);
    float* op = out + (size_t)b * CHW + pbase + pl;
    #pragma unroll 1
    for (int t = 0; t < 16; ++t) {
      const int co = j * 16 + t;
      const float* w = Wo + co * CN;     // uniform per wave -> scalar loads
      float a0 = bo[co], a1 = 0.f, a2 = 0.f, a3 = 0.f;
      #pragma unroll
      for (int c = 0; c < CN; c += 4) {
        a0 = fmaf(w[c+0], u[c+0], a0);
        a1 = fmaf(w[c+1], u[c+1], a1);
        a2 = fmaf(w[c+2], u[c+2], a2);
        a3 = fmaf(w[c+3], u[c+3], a3);
      }
      op[co * HWN] = fmaxf((a0 + a1) + (a2 + a3), 0.f);   // coalesced store
    }
  }
}

extern "C" void kernel_launch(void* const* d_in, const int* in_sizes, int n_in,
                              void* d_out, int out_size, void* d_ws, size_t ws_size,
                              hipStream_t stream) {
  (void)in_sizes; (void)n_in; (void)d_ws; (void)ws_size; (void)out_size;
  const float* xx   = (const float*)d_in[0];
  const float* rims = (const float*)d_in[1];
  const float* Wk   = (const float*)d_in[2];
  const float* bk   = (const float*)d_in[3];
  const float* Wv   = (const float*)d_in[4];
  const float* bv   = (const float*)d_in[5];
  const float* Wq   = (const float*)d_in[6];
  const float* bq   = (const float*)d_in[7];
  const float* Wm   = (const float*)d_in[8];
  const float* bm   = (const float*)d_in[9];
  const float* Wo   = (const float*)d_in[10];
  const float* bo   = (const float*)d_in[11];
  float* outp = (float*)d_out;

  rims_fused<<<dim3(NPIX / 64), dim3(256), 0, stream>>>(
      xx, rims, Wk, bk, Wv, bv, Wq, bq, Wm, bm, Wo, bo, outp);
}